// Round 5
// baseline (2221.404 us; speedup 1.0000x reference)
//
#include <hip/hip_runtime.h>
#include <math.h>

#define THREADS 256
#define SH 7                 // bin width = 128 nodes
#define BINW 128
#define MAXBIN 2048          // supports N <= 262144 (matches 18-bit row pack)
#define CHUNK 8192           // edges per block in binning passes
#define K4CAP 12288          // pairs buffered in LDS by csr_place (48KB); avg bin ~8.2K
#define SLOTU 50000          // scratch slot (uints) for oversized bins (never expected)

// ======================= atomic-free CSR build =======================

__global__ void hist_kernel(const int* __restrict__ row, const int* __restrict__ col,
                            int* __restrict__ Dcol, int* __restrict__ Drow,
                            int E, int NBIN) {
    __shared__ int hc[MAXBIN], hr[MAXBIN];
    for (int i = threadIdx.x; i < NBIN; i += THREADS) { hc[i] = 0; hr[i] = 0; }
    __syncthreads();
    int base = blockIdx.x * CHUNK;
#pragma unroll
    for (int k = 0; k < CHUNK / THREADS; ++k) {
        int e = base + k * THREADS + threadIdx.x;
        if (e < E) {
            atomicAdd(&hc[col[e] >> SH], 1);
            atomicAdd(&hr[row[e] >> SH], 1);
        }
    }
    __syncthreads();
    size_t ob = (size_t)blockIdx.x * NBIN;
    for (int i = threadIdx.x; i < NBIN; i += THREADS) {
        Dcol[ob + i] = hc[i];
        Drow[ob + i] = hr[i];
    }
}

__global__ void scan_col_kernel(int* __restrict__ D, int* __restrict__ binTot,
                                int NBLK, int NBIN) {
    __shared__ int tmp[THREADS];
    int b = blockIdx.x;
    int carry = 0;
    for (int base = 0; base < NBLK; base += THREADS) {
        int idx = base + threadIdx.x;
        int v = (idx < NBLK) ? D[(size_t)idx * NBIN + b] : 0;
        tmp[threadIdx.x] = v;
        __syncthreads();
        for (int d = 1; d < THREADS; d <<= 1) {
            int u = (threadIdx.x >= d) ? tmp[threadIdx.x - d] : 0;
            __syncthreads();
            tmp[threadIdx.x] += u;
            __syncthreads();
        }
        if (idx < NBLK) D[(size_t)idx * NBIN + b] = carry + tmp[threadIdx.x] - v;
        carry += tmp[THREADS - 1];
        __syncthreads();
    }
    if (threadIdx.x == 0) binTot[b] = carry;
}

__global__ void scan_bins_kernel(const int* __restrict__ binTot, int* __restrict__ binBase, int NBIN) {
    __shared__ int tmp[1024];
    int carry = 0;
    for (int base = 0; base < NBIN; base += 1024) {
        int i = base + threadIdx.x;
        int v = (i < NBIN) ? binTot[i] : 0;
        tmp[threadIdx.x] = v;
        __syncthreads();
        for (int d = 1; d < 1024; d <<= 1) {
            int u = (threadIdx.x >= d) ? tmp[threadIdx.x - d] : 0;
            __syncthreads();
            tmp[threadIdx.x] += u;
            __syncthreads();
        }
        if (i < NBIN) binBase[i] = carry + tmp[threadIdx.x] - v;
        carry += tmp[1023];
        __syncthreads();
    }
    if (threadIdx.x == 0) binBase[NBIN] = carry;
}

__global__ void add_base_kernel(int* __restrict__ D, const int* __restrict__ binBase,
                                int NBLK, int NBIN) {
    size_t i = (size_t)blockIdx.x * blockDim.x + threadIdx.x;
    if (i < (size_t)NBLK * NBIN) D[i] += binBase[i % NBIN];
}

__global__ void scatter_kernel(const int* __restrict__ row, const int* __restrict__ col,
                               const int* __restrict__ Dcol, const int* __restrict__ Drow,
                               unsigned int* __restrict__ A, unsigned char* __restrict__ Cu8,
                               int E, int NBIN) {
    __shared__ int lc[MAXBIN], lr[MAXBIN];
    size_t ob = (size_t)blockIdx.x * NBIN;
    for (int i = threadIdx.x; i < NBIN; i += THREADS) { lc[i] = Dcol[ob + i]; lr[i] = Drow[ob + i]; }
    __syncthreads();
    int base = blockIdx.x * CHUNK;
#pragma unroll
    for (int k = 0; k < CHUNK / THREADS; ++k) {
        int e = base + k * THREADS + threadIdx.x;
        if (e < E) {
            int c = col[e], r = row[e];
            int pc = atomicAdd(&lc[c >> SH], 1);
            A[pc] = (unsigned int)r | ((unsigned int)(c & (BINW - 1)) << 18);
            int pr = atomicAdd(&lr[r >> SH], 1);
            Cu8[pr] = (unsigned char)(r & (BINW - 1));
        }
    }
}

__global__ void deg_bins_kernel(const unsigned char* __restrict__ Cu8,
                                const int* __restrict__ binBaseR,
                                float* __restrict__ dis, int N) {
    __shared__ int cnt[BINW];
    int b = blockIdx.x;
    if (threadIdx.x < BINW) cnt[threadIdx.x] = 0;
    __syncthreads();
    int p0 = binBaseR[b], p1 = binBaseR[b + 1];
    for (int i = p0 + threadIdx.x; i < p1; i += THREADS)
        atomicAdd(&cnt[Cu8[i]], 1);
    __syncthreads();
    int node = (b << SH) + threadIdx.x;
    if (threadIdx.x < BINW && node < N) {
        int c = cnt[threadIdx.x];
        dis[node] = c > 0 ? rsqrtf((float)c) : 0.f;
    }
}

__global__ void csr_place_kernel(unsigned int* __restrict__ A,
                                 const int* __restrict__ binBaseC,
                                 int* __restrict__ off,
                                 unsigned int* __restrict__ scratch,
                                 int N) {
    __shared__ unsigned int buf[K4CAP];
    __shared__ int cnt[BINW], pref[BINW], tmp[BINW];
    int b = blockIdx.x;
    int t = threadIdx.x;
    int p0 = binBaseC[b], p1 = binBaseC[b + 1];
    int sz = p1 - p0;
    const unsigned int* src;
    if (sz <= K4CAP) {
        for (int i = t; i < sz; i += THREADS) buf[i] = A[p0 + i];
        src = buf;
    } else {
        unsigned int* sc = scratch + (size_t)(b & 63) * SLOTU;
        for (int i = t; i < sz && i < SLOTU; i += THREADS) sc[i] = A[p0 + i];
        src = sc;
    }
    if (t < BINW) cnt[t] = 0;
    __syncthreads();
    for (int i = t; i < sz; i += THREADS)
        atomicAdd(&cnt[(src[i] >> 18) & (BINW - 1)], 1);
    __syncthreads();
    int v = (t < BINW) ? cnt[t] : 0;
    if (t < BINW) tmp[t] = v;
    __syncthreads();
    for (int d = 1; d < BINW; d <<= 1) {
        int u = (t >= d && t < BINW) ? tmp[t - d] : 0;
        __syncthreads();
        if (t < BINW) tmp[t] += u;
        __syncthreads();
    }
    if (t < BINW) pref[t] = tmp[t] - v;
    int node = (b << SH) + t;
    if (t < BINW && node < N) off[node] = p0 + pref[t];
    __syncthreads();
    for (int i = t; i < sz; i += THREADS) {
        unsigned int a = src[i];
        int cl = (a >> 18) & (BINW - 1);
        int p = atomicAdd(&pref[cl], 1);
        A[(size_t)p0 + p] = a & 0x3FFFFu;
    }
}

// ======================= feature-blocked L2-resident aggregation =======================

// pre-scale x by dis, emit feature-blocked [2][N] float4
__global__ void xs_kernel(const float* __restrict__ x, const float* __restrict__ dis,
                          float4* __restrict__ xs4, int N) {
    int c = blockIdx.x * blockDim.x + threadIdx.x;
    if (c >= N) return;
    float d = dis[c];
    const float4* xr = reinterpret_cast<const float4*>(x + (size_t)c * 8);
    float4 a = xr[0], b = xr[1];
    xs4[c]             = make_float4(d * a.x, d * a.y, d * a.z, d * a.w);
    xs4[(size_t)N + c] = make_float4(d * b.x, d * b.y, d * b.z, d * b.w);
}

// one 4-feature aggregation pass; src4 block is ~3.2MB -> L2-resident.
// csr/off streamed nontemporally to avoid evicting the gather array.
__global__ void agg_pass_kernel(const int* __restrict__ off, const int* __restrict__ csr,
                                const float4* __restrict__ src4, float4* __restrict__ dst4,
                                int N, int E) {
    int c = blockIdx.x * blockDim.x + threadIdx.x;
    if (c >= N) return;
    int p0 = __builtin_nontemporal_load(&off[c]);
    int p1 = (c == N - 1) ? E : __builtin_nontemporal_load(&off[c + 1]);
    float ax = 0.f, ay = 0.f, az = 0.f, aw = 0.f;
    for (int p = p0; p < p1; ++p) {
        int s = __builtin_nontemporal_load(&csr[p]);
        float4 q = src4[s];
        ax += q.x; ay += q.y; az += q.z; aw += q.w;
    }
    dst4[c] = make_float4(ax, ay, az, aw);
}

// dense layer1 + relu; emits h1s = dis*h1 (blocked, for layer-2 gather)
// and P0 = b2 + h1 @ W2_0 (own-node term of layer 2, exact)
__global__ void dense1_kernel(const float* __restrict__ x, const float4* __restrict__ txp4,
                              const float* __restrict__ dis,
                              const float* __restrict__ W0, const float* __restrict__ W1,
                              const float* __restrict__ b1,
                              const float* __restrict__ W20, const float* __restrict__ b2,
                              float4* __restrict__ h1s4, float* __restrict__ P0, int N) {
    __shared__ float sW0[128], sW1[128], sb1[16], sW20[256], sb2[16];
    for (int i = threadIdx.x; i < 128; i += blockDim.x) { sW0[i] = W0[i]; sW1[i] = W1[i]; }
    for (int i = threadIdx.x; i < 256; i += blockDim.x) sW20[i] = W20[i];
    if (threadIdx.x < 16) { sb1[threadIdx.x] = b1[threadIdx.x]; sb2[threadIdx.x] = b2[threadIdx.x]; }
    __syncthreads();
    int c = blockIdx.x * blockDim.x + threadIdx.x;
    if (c >= N) return;
    float xa[8];
    const float4* xr = reinterpret_cast<const float4*>(x + (size_t)c * 8);
    float4 a = xr[0], bb = xr[1];
    xa[0] = a.x; xa[1] = a.y; xa[2] = a.z; xa[3] = a.w;
    xa[4] = bb.x; xa[5] = bb.y; xa[6] = bb.z; xa[7] = bb.w;
    float tx[8];
    float4 t0 = txp4[c], t1 = txp4[(size_t)N + c];
    tx[0] = t0.x; tx[1] = t0.y; tx[2] = t0.z; tx[3] = t0.w;
    tx[4] = t1.x; tx[5] = t1.y; tx[6] = t1.z; tx[7] = t1.w;
    float d = dis[c], sc = -d;
    float acc[16];
#pragma unroll
    for (int o = 0; o < 16; ++o) acc[o] = sb1[o];
#pragma unroll
    for (int f = 0; f < 8; ++f) {
        float xv = xa[f], tv = sc * tx[f];
#pragma unroll
        for (int o = 0; o < 16; ++o) acc[o] += xv * sW0[f * 16 + o] + tv * sW1[f * 16 + o];
    }
    float h[16];
#pragma unroll
    for (int o = 0; o < 16; ++o) h[o] = fmaxf(acc[o], 0.f);
#pragma unroll
    for (int fb = 0; fb < 4; ++fb)
        h1s4[(size_t)fb * N + c] = make_float4(d * h[fb * 4 + 0], d * h[fb * 4 + 1],
                                               d * h[fb * 4 + 2], d * h[fb * 4 + 3]);
    float p[16];
#pragma unroll
    for (int o = 0; o < 16; ++o) p[o] = sb2[o];
#pragma unroll
    for (int f = 0; f < 16; ++f) {
        float hv = h[f];
#pragma unroll
        for (int o = 0; o < 16; ++o) p[o] += hv * sW20[f * 16 + o];
    }
    float4* pp = reinterpret_cast<float4*>(P0 + (size_t)c * 16);
#pragma unroll
    for (int v = 0; v < 4; ++v)
        pp[v] = make_float4(p[v * 4 + 0], p[v * 4 + 1], p[v * 4 + 2], p[v * 4 + 3]);
}

// dense layer2 (tx side) + relu + readout
__global__ void dense2_kernel(const float* __restrict__ P0, const float4* __restrict__ txp4,
                              const float* __restrict__ dis,
                              const float* __restrict__ W21, const float* __restrict__ Wr,
                              const float* __restrict__ br, float* __restrict__ s, int N) {
    __shared__ float sW1[256], sWr[16], sbr;
    for (int i = threadIdx.x; i < 256; i += blockDim.x) sW1[i] = W21[i];
    if (threadIdx.x < 16) sWr[threadIdx.x] = Wr[threadIdx.x];
    if (threadIdx.x == 0) sbr = br[0];
    __syncthreads();
    int c = blockIdx.x * blockDim.x + threadIdx.x;
    if (c >= N) return;
    float tx[16];
#pragma unroll
    for (int fb = 0; fb < 4; ++fb) {
        float4 q = txp4[(size_t)fb * N + c];
        tx[fb * 4 + 0] = q.x; tx[fb * 4 + 1] = q.y; tx[fb * 4 + 2] = q.z; tx[fb * 4 + 3] = q.w;
    }
    float sc = -dis[c];
    float acc[16];
    const float4* pr = reinterpret_cast<const float4*>(P0 + (size_t)c * 16);
#pragma unroll
    for (int v = 0; v < 4; ++v) {
        float4 q = pr[v];
        acc[v * 4 + 0] = q.x; acc[v * 4 + 1] = q.y; acc[v * 4 + 2] = q.z; acc[v * 4 + 3] = q.w;
    }
#pragma unroll
    for (int f = 0; f < 16; ++f) {
        float tv = sc * tx[f];
#pragma unroll
        for (int o = 0; o < 16; ++o) acc[o] += tv * sW1[f * 16 + o];
    }
    float sv = sbr;
#pragma unroll
    for (int o = 0; o < 16; ++o) sv += fmaxf(acc[o], 0.f) * sWr[o];
    s[c] = sv;
}

__global__ void softmax_kernel(const float* __restrict__ s, const int* __restrict__ batch,
                               float* __restrict__ out, int N) {
    int g = blockIdx.x;
    __shared__ float red[THREADS];
    int lo, hi;
    { int a = 0, b = N; while (a < b) { int mid = (a + b) >> 1; if (batch[mid] < g) a = mid + 1; else b = mid; } lo = a; }
    { int a = lo, b = N; while (a < b) { int mid = (a + b) >> 1; if (batch[mid] < g + 1) a = mid + 1; else b = mid; } hi = a; }
    float mx = -INFINITY;
    for (int i = lo + threadIdx.x; i < hi; i += THREADS) mx = fmaxf(mx, s[i]);
    red[threadIdx.x] = mx;
    __syncthreads();
    for (int d = THREADS / 2; d > 0; d >>= 1) {
        if (threadIdx.x < d) red[threadIdx.x] = fmaxf(red[threadIdx.x], red[threadIdx.x + d]);
        __syncthreads();
    }
    mx = red[0];
    __syncthreads();
    float sum = 0.f;
    for (int i = lo + threadIdx.x; i < hi; i += THREADS) sum += expf(s[i] - mx);
    red[threadIdx.x] = sum;
    __syncthreads();
    for (int d = THREADS / 2; d > 0; d >>= 1) {
        if (threadIdx.x < d) red[threadIdx.x] += red[threadIdx.x + d];
        __syncthreads();
    }
    float inv = 1.f / red[0];
    for (int i = lo + threadIdx.x; i < hi; i += THREADS) out[i] = expf(s[i] - mx) * inv;
}

// ======================= fallback: round-2 atomic CSR build + fused gathers =======================

__global__ void deg_cnt_kernel(const int* __restrict__ row, const int* __restrict__ col,
                               int* __restrict__ deg_i, int* __restrict__ cnt, int E) {
    int e = blockIdx.x * blockDim.x + threadIdx.x;
    if (e >= E) return;
    atomicAdd(&deg_i[row[e]], 1);
    atomicAdd(&cnt[col[e]], 1);
}

__global__ void dis_kernel_i(const int* __restrict__ deg_i, float* __restrict__ dis, int N) {
    int i = blockIdx.x * blockDim.x + threadIdx.x;
    if (i < N) {
        int d = deg_i[i];
        dis[i] = d > 0 ? rsqrtf((float)d) : 0.f;
    }
}

__global__ void scan1_kernel(const int* __restrict__ cnt, int* __restrict__ off,
                             int* __restrict__ bsum, int n) {
    __shared__ int tmp[THREADS];
    int i = blockIdx.x * THREADS + threadIdx.x;
    int v = (i < n) ? cnt[i] : 0;
    tmp[threadIdx.x] = v;
    __syncthreads();
    for (int d = 1; d < THREADS; d <<= 1) {
        int t = (threadIdx.x >= d) ? tmp[threadIdx.x - d] : 0;
        __syncthreads();
        tmp[threadIdx.x] += t;
        __syncthreads();
    }
    if (i < n) off[i] = tmp[threadIdx.x] - v;
    if (threadIdx.x == THREADS - 1) bsum[blockIdx.x] = tmp[threadIdx.x];
}

__global__ void scan2_kernel(int* __restrict__ bsum, int nb) {
    __shared__ int tmp[1024];
    int carry = 0;
    for (int base = 0; base < nb; base += 1024) {
        int i = base + threadIdx.x;
        int v = (i < nb) ? bsum[i] : 0;
        tmp[threadIdx.x] = v;
        __syncthreads();
        for (int d = 1; d < 1024; d <<= 1) {
            int t = (threadIdx.x >= d) ? tmp[threadIdx.x - d] : 0;
            __syncthreads();
            tmp[threadIdx.x] += t;
            __syncthreads();
        }
        if (i < nb) bsum[i] = carry + tmp[threadIdx.x] - v;
        carry += tmp[1023];
        __syncthreads();
    }
}

__global__ void scan3_kernel(int* __restrict__ off, const int* __restrict__ bsum, int n) {
    int i = blockIdx.x * THREADS + threadIdx.x;
    if (i < n) off[i] += bsum[blockIdx.x];
}

__global__ void fill_csr_kernel(const int* __restrict__ row, const int* __restrict__ col,
                                const int* __restrict__ off, int* __restrict__ fill,
                                int* __restrict__ csr_src, int E) {
    int e = blockIdx.x * blockDim.x + threadIdx.x;
    if (e >= E) return;
    int c = col[e];
    int p = off[c] + atomicAdd(&fill[c], 1);
    csr_src[p] = row[e];
}

__global__ void gather_dense1_kernel(const int* __restrict__ off, const int* __restrict__ csr_src,
                                     const float* __restrict__ dis, const float* __restrict__ x,
                                     const float* __restrict__ W0, const float* __restrict__ W1,
                                     const float* __restrict__ b, float* __restrict__ h1,
                                     int N, int E) {
    __shared__ float sW0[8 * 16], sW1[8 * 16], sb[16];
    for (int i = threadIdx.x; i < 128; i += blockDim.x) { sW0[i] = W0[i]; sW1[i] = W1[i]; }
    if (threadIdx.x < 16) sb[threadIdx.x] = b[threadIdx.x];
    __syncthreads();
    int c = blockIdx.x * blockDim.x + threadIdx.x;
    if (c >= N) return;
    int p0 = off[c], p1 = (c == N - 1) ? E : off[c + 1];
    float tx[8] = {0, 0, 0, 0, 0, 0, 0, 0};
    for (int p = p0; p < p1; ++p) {
        int src = csr_src[p];
        float wv = dis[src];
        const float4* fr = reinterpret_cast<const float4*>(x + (size_t)src * 8);
        float4 a = fr[0], bb = fr[1];
        tx[0] += wv * a.x;  tx[1] += wv * a.y;  tx[2] += wv * a.z;  tx[3] += wv * a.w;
        tx[4] += wv * bb.x; tx[5] += wv * bb.y; tx[6] += wv * bb.z; tx[7] += wv * bb.w;
    }
    float sc = -dis[c];
    float xa[8];
    const float4* xr = reinterpret_cast<const float4*>(x + (size_t)c * 8);
    float4 a = xr[0], bb = xr[1];
    xa[0] = a.x; xa[1] = a.y; xa[2] = a.z; xa[3] = a.w;
    xa[4] = bb.x; xa[5] = bb.y; xa[6] = bb.z; xa[7] = bb.w;
    float acc[16];
#pragma unroll
    for (int o = 0; o < 16; ++o) acc[o] = sb[o];
#pragma unroll
    for (int f = 0; f < 8; ++f) {
        float xv = xa[f], tv = sc * tx[f];
#pragma unroll
        for (int o = 0; o < 16; ++o) acc[o] += xv * sW0[f * 16 + o] + tv * sW1[f * 16 + o];
    }
    float4* outp = reinterpret_cast<float4*>(h1 + (size_t)c * 16);
#pragma unroll
    for (int v = 0; v < 4; ++v) {
        float4 q;
        q.x = fmaxf(acc[v * 4 + 0], 0.f);
        q.y = fmaxf(acc[v * 4 + 1], 0.f);
        q.z = fmaxf(acc[v * 4 + 2], 0.f);
        q.w = fmaxf(acc[v * 4 + 3], 0.f);
        outp[v] = q;
    }
}

__global__ void gather_dense2_kernel(const int* __restrict__ off, const int* __restrict__ csr_src,
                                     const float* __restrict__ dis, const float* __restrict__ h1,
                                     const float* __restrict__ W0, const float* __restrict__ W1,
                                     const float* __restrict__ b, const float* __restrict__ Wr,
                                     const float* __restrict__ br, float* __restrict__ s,
                                     int N, int E) {
    __shared__ float sW0[16 * 16], sW1[16 * 16], sb[16], sWr[16], sbr;
    for (int i = threadIdx.x; i < 256; i += blockDim.x) { sW0[i] = W0[i]; sW1[i] = W1[i]; }
    if (threadIdx.x < 16) { sb[threadIdx.x] = b[threadIdx.x]; sWr[threadIdx.x] = Wr[threadIdx.x]; }
    if (threadIdx.x == 0) sbr = br[0];
    __syncthreads();
    int c = blockIdx.x * blockDim.x + threadIdx.x;
    if (c >= N) return;
    int p0 = off[c], p1 = (c == N - 1) ? E : off[c + 1];
    float tx[16];
#pragma unroll
    for (int o = 0; o < 16; ++o) tx[o] = 0.f;
    for (int p = p0; p < p1; ++p) {
        int src = csr_src[p];
        float wv = dis[src];
        const float4* fr = reinterpret_cast<const float4*>(h1 + (size_t)src * 16);
#pragma unroll
        for (int v = 0; v < 4; ++v) {
            float4 q = fr[v];
            tx[v * 4 + 0] += wv * q.x;
            tx[v * 4 + 1] += wv * q.y;
            tx[v * 4 + 2] += wv * q.z;
            tx[v * 4 + 3] += wv * q.w;
        }
    }
    float sc = -dis[c];
    float ha[16];
    const float4* hr = reinterpret_cast<const float4*>(h1 + (size_t)c * 16);
#pragma unroll
    for (int v = 0; v < 4; ++v) {
        float4 q = hr[v];
        ha[v * 4 + 0] = q.x; ha[v * 4 + 1] = q.y; ha[v * 4 + 2] = q.z; ha[v * 4 + 3] = q.w;
    }
    float acc[16];
#pragma unroll
    for (int o = 0; o < 16; ++o) acc[o] = sb[o];
#pragma unroll
    for (int f = 0; f < 16; ++f) {
        float hv = ha[f], tv = sc * tx[f];
#pragma unroll
        for (int o = 0; o < 16; ++o) acc[o] += hv * sW0[f * 16 + o] + tv * sW1[f * 16 + o];
    }
    float sv = sbr;
#pragma unroll
    for (int o = 0; o < 16; ++o) sv += fmaxf(acc[o], 0.f) * sWr[o];
    s[c] = sv;
}

// ======================= launch =======================

extern "C" void kernel_launch(void* const* d_in, const int* in_sizes, int n_in,
                              void* d_out, int out_size, void* d_ws, size_t ws_size,
                              hipStream_t stream) {
    const float* x     = (const float*)d_in[0];
    const int*   ei    = (const int*)d_in[1];
    const int*   batch = (const int*)d_in[2];
    const float* W1_0  = (const float*)d_in[3];
    const float* W1_1  = (const float*)d_in[4];
    const float* b1    = (const float*)d_in[5];
    const float* W2_0  = (const float*)d_in[6];
    const float* W2_1  = (const float*)d_in[7];
    const float* b2    = (const float*)d_in[8];
    const float* Wr    = (const float*)d_in[9];
    const float* br    = (const float*)d_in[10];
    float* out = (float*)d_out;

    const int N = in_sizes[2];
    const int E = in_sizes[1] / 2;
    const int G = 256;
    const int* row = ei;
    const int* col = ei + E;

    const int gN = (N + THREADS - 1) / THREADS;
    const int gE = (E + THREADS - 1) / THREADS;
    const int NBIN = (N + BINW - 1) >> SH;
    const int NBLK = (E + CHUNK - 1) / CHUNK;

    // fast-path layout (unions keyed to kernel timeline):
    //  pA: pairs->csr | pCu8H: Cu8 (build) ∪ h1s blocked (layers) | off/dis/s | bins
    //  pU1: Dcol+Drow (build) ∪ xs blocked + P0 (layers)
    //  pU2: csr_place scratch ∪ txp blocked
    size_t offB = 0;
    auto alloc = [&](size_t bytes) { size_t p = offB; offB += (bytes + 255) & ~(size_t)255; return p; };
    auto maxz = [](size_t a, size_t b) { return a > b ? a : b; };
    size_t pA    = alloc((size_t)E * 4);
    size_t pCu8H = alloc(maxz((size_t)E, (size_t)64 * N));
    size_t pOff  = alloc((size_t)N * 4);
    size_t pDis  = alloc((size_t)N * 4);
    size_t pS    = alloc((size_t)N * 4);
    size_t pTotC = alloc((size_t)NBIN * 4);
    size_t pBasC = alloc((size_t)(NBIN + 1) * 4);
    size_t pTotR = alloc((size_t)NBIN * 4);
    size_t pBasR = alloc((size_t)(NBIN + 1) * 4);
    size_t pU1   = alloc(maxz((size_t)2 * NBLK * NBIN * 4, (size_t)96 * N));
    size_t pU2   = alloc(maxz((size_t)64 * SLOTU * 4, (size_t)64 * N));
    size_t need_fast = offB;

    if (N <= (1 << 18) && NBIN <= MAXBIN && ws_size >= need_fast) {
        char* base = (char*)d_ws;
        unsigned int* A    = (unsigned int*)(base + pA);
        unsigned char* Cu8 = (unsigned char*)(base + pCu8H);
        float4* h1s4       = (float4*)(base + pCu8H);
        int* off   = (int*)(base + pOff);
        float* dis = (float*)(base + pDis);
        float* s   = (float*)(base + pS);
        int* totC  = (int*)(base + pTotC);
        int* basC  = (int*)(base + pBasC);
        int* totR  = (int*)(base + pTotR);
        int* basR  = (int*)(base + pBasR);
        int* Dcol  = (int*)(base + pU1);
        int* Drow  = Dcol + (size_t)NBLK * NBIN;
        float4* xs4 = (float4*)(base + pU1);
        float* P0   = (float*)(base + pU1 + (size_t)32 * N);
        unsigned int* scratch = (unsigned int*)(base + pU2);
        float4* txp4          = (float4*)(base + pU2);

        int gAB = (int)(((size_t)NBLK * NBIN + THREADS - 1) / THREADS);

        // build CSR (atomic-free, proven)
        hist_kernel<<<NBLK, THREADS, 0, stream>>>(row, col, Dcol, Drow, E, NBIN);
        scan_col_kernel<<<NBIN, THREADS, 0, stream>>>(Dcol, totC, NBLK, NBIN);
        scan_col_kernel<<<NBIN, THREADS, 0, stream>>>(Drow, totR, NBLK, NBIN);
        scan_bins_kernel<<<1, 1024, 0, stream>>>(totC, basC, NBIN);
        scan_bins_kernel<<<1, 1024, 0, stream>>>(totR, basR, NBIN);
        add_base_kernel<<<gAB, THREADS, 0, stream>>>(Dcol, basC, NBLK, NBIN);
        add_base_kernel<<<gAB, THREADS, 0, stream>>>(Drow, basR, NBLK, NBIN);
        scatter_kernel<<<NBLK, THREADS, 0, stream>>>(row, col, Dcol, Drow, A, Cu8, E, NBIN);
        deg_bins_kernel<<<NBIN, THREADS, 0, stream>>>(Cu8, basR, dis, N);
        csr_place_kernel<<<NBIN, THREADS, 0, stream>>>(A, basC, off, scratch, N);

        // layer 1: blocked aggregation (L2-resident 3.2MB blocks) + dense
        xs_kernel<<<gN, THREADS, 0, stream>>>(x, dis, xs4, N);
        for (int fb = 0; fb < 2; ++fb)
            agg_pass_kernel<<<gN, THREADS, 0, stream>>>(off, (const int*)A,
                                                        xs4 + (size_t)fb * N,
                                                        txp4 + (size_t)fb * N, N, E);
        dense1_kernel<<<gN, THREADS, 0, stream>>>(x, txp4, dis, W1_0, W1_1, b1, W2_0, b2,
                                                  h1s4, P0, N);
        // layer 2: blocked aggregation + dense + readout
        for (int fb = 0; fb < 4; ++fb)
            agg_pass_kernel<<<gN, THREADS, 0, stream>>>(off, (const int*)A,
                                                        h1s4 + (size_t)fb * N,
                                                        txp4 + (size_t)fb * N, N, E);
        dense2_kernel<<<gN, THREADS, 0, stream>>>(P0, txp4, dis, W2_1, Wr, br, s, N);
        softmax_kernel<<<G, THREADS, 0, stream>>>(s, batch, out, N);
    } else {
        // fallback: round-2 atomic CSR path
        int* deg_i = (int*)d_ws;
        int* cnt   = deg_i + N;
        int* fill  = cnt + N;
        int* off   = fill + N;
        int* bsum  = off + N;
        float* dis = (float*)(bsum + 1024);
        float* h1  = dis + N;
        float* s   = h1 + (size_t)16 * N;
        int* csr   = (int*)(s + N);

        hipMemsetAsync(deg_i, 0, sizeof(int) * (size_t)3 * N, stream);

        deg_cnt_kernel<<<gE, THREADS, 0, stream>>>(row, col, deg_i, cnt, E);
        dis_kernel_i<<<gN, THREADS, 0, stream>>>(deg_i, dis, N);
        scan1_kernel<<<gN, THREADS, 0, stream>>>(cnt, off, bsum, N);
        scan2_kernel<<<1, 1024, 0, stream>>>(bsum, gN);
        scan3_kernel<<<gN, THREADS, 0, stream>>>(off, bsum, N);
        fill_csr_kernel<<<gE, THREADS, 0, stream>>>(row, col, off, fill, csr, E);
        gather_dense1_kernel<<<gN, THREADS, 0, stream>>>(off, csr, dis, x, W1_0, W1_1, b1, h1, N, E);
        gather_dense2_kernel<<<gN, THREADS, 0, stream>>>(off, csr, dis, h1, W2_0, W2_1, b2, Wr, br, s, N, E);
        softmax_kernel<<<G, THREADS, 0, stream>>>(s, batch, out, N);
    }
}

// Round 6
// 1052.594 us; speedup vs baseline: 2.1104x; 2.1104x over previous
//
#include <hip/hip_runtime.h>
#include <math.h>

#define THREADS 256
#define SH 7                 // bin width = 128 nodes
#define BINW 128
#define MAXBIN 2048          // supports N <= 262144 (matches 18-bit row pack)
#define CHUNK 8192           // edges per block in binning passes
#define K4CAP 12288          // pairs buffered in LDS by csr_place (48KB); avg bin ~8.2K
#define SLOTU 50000          // scratch slot (uints) for oversized bins (never expected)

// ======================= atomic-free CSR build =======================

__global__ void hist_kernel(const int* __restrict__ row, const int* __restrict__ col,
                            int* __restrict__ Dcol, int* __restrict__ Drow,
                            int E, int NBIN) {
    __shared__ int hc[MAXBIN], hr[MAXBIN];
    for (int i = threadIdx.x; i < NBIN; i += THREADS) { hc[i] = 0; hr[i] = 0; }
    __syncthreads();
    int base = blockIdx.x * CHUNK;
#pragma unroll
    for (int k = 0; k < CHUNK / THREADS; ++k) {
        int e = base + k * THREADS + threadIdx.x;
        if (e < E) {
            atomicAdd(&hc[col[e] >> SH], 1);
            atomicAdd(&hr[row[e] >> SH], 1);
        }
    }
    __syncthreads();
    size_t ob = (size_t)blockIdx.x * NBIN;
    for (int i = threadIdx.x; i < NBIN; i += THREADS) {
        Dcol[ob + i] = hc[i];
        Drow[ob + i] = hr[i];
    }
}

__global__ void scan_col_kernel(int* __restrict__ D, int* __restrict__ binTot,
                                int NBLK, int NBIN) {
    __shared__ int tmp[THREADS];
    int b = blockIdx.x;
    int carry = 0;
    for (int base = 0; base < NBLK; base += THREADS) {
        int idx = base + threadIdx.x;
        int v = (idx < NBLK) ? D[(size_t)idx * NBIN + b] : 0;
        tmp[threadIdx.x] = v;
        __syncthreads();
        for (int d = 1; d < THREADS; d <<= 1) {
            int u = (threadIdx.x >= d) ? tmp[threadIdx.x - d] : 0;
            __syncthreads();
            tmp[threadIdx.x] += u;
            __syncthreads();
        }
        if (idx < NBLK) D[(size_t)idx * NBIN + b] = carry + tmp[threadIdx.x] - v;
        carry += tmp[THREADS - 1];
        __syncthreads();
    }
    if (threadIdx.x == 0) binTot[b] = carry;
}

__global__ void scan_bins_kernel(const int* __restrict__ binTot, int* __restrict__ binBase, int NBIN) {
    __shared__ int tmp[1024];
    int carry = 0;
    for (int base = 0; base < NBIN; base += 1024) {
        int i = base + threadIdx.x;
        int v = (i < NBIN) ? binTot[i] : 0;
        tmp[threadIdx.x] = v;
        __syncthreads();
        for (int d = 1; d < 1024; d <<= 1) {
            int u = (threadIdx.x >= d) ? tmp[threadIdx.x - d] : 0;
            __syncthreads();
            tmp[threadIdx.x] += u;
            __syncthreads();
        }
        if (i < NBIN) binBase[i] = carry + tmp[threadIdx.x] - v;
        carry += tmp[1023];
        __syncthreads();
    }
    if (threadIdx.x == 0) binBase[NBIN] = carry;
}

__global__ void add_base_kernel(int* __restrict__ D, const int* __restrict__ binBase,
                                int NBLK, int NBIN) {
    size_t i = (size_t)blockIdx.x * blockDim.x + threadIdx.x;
    if (i < (size_t)NBLK * NBIN) D[i] += binBase[i % NBIN];
}

__global__ void scatter_kernel(const int* __restrict__ row, const int* __restrict__ col,
                               const int* __restrict__ Dcol, const int* __restrict__ Drow,
                               unsigned int* __restrict__ A, unsigned char* __restrict__ Cu8,
                               int E, int NBIN) {
    __shared__ int lc[MAXBIN], lr[MAXBIN];
    size_t ob = (size_t)blockIdx.x * NBIN;
    for (int i = threadIdx.x; i < NBIN; i += THREADS) { lc[i] = Dcol[ob + i]; lr[i] = Drow[ob + i]; }
    __syncthreads();
    int base = blockIdx.x * CHUNK;
#pragma unroll
    for (int k = 0; k < CHUNK / THREADS; ++k) {
        int e = base + k * THREADS + threadIdx.x;
        if (e < E) {
            int c = col[e], r = row[e];
            int pc = atomicAdd(&lc[c >> SH], 1);
            A[pc] = (unsigned int)r | ((unsigned int)(c & (BINW - 1)) << 18);
            int pr = atomicAdd(&lr[r >> SH], 1);
            Cu8[pr] = (unsigned char)(r & (BINW - 1));
        }
    }
}

__global__ void deg_bins_kernel(const unsigned char* __restrict__ Cu8,
                                const int* __restrict__ binBaseR,
                                float* __restrict__ dis, int N) {
    __shared__ int cnt[BINW];
    int b = blockIdx.x;
    if (threadIdx.x < BINW) cnt[threadIdx.x] = 0;
    __syncthreads();
    int p0 = binBaseR[b], p1 = binBaseR[b + 1];
    for (int i = p0 + threadIdx.x; i < p1; i += THREADS)
        atomicAdd(&cnt[Cu8[i]], 1);
    __syncthreads();
    int node = (b << SH) + threadIdx.x;
    if (threadIdx.x < BINW && node < N) {
        int c = cnt[threadIdx.x];
        dis[node] = c > 0 ? rsqrtf((float)c) : 0.f;
    }
}

__global__ void csr_place_kernel(unsigned int* __restrict__ A,
                                 const int* __restrict__ binBaseC,
                                 int* __restrict__ off,
                                 unsigned int* __restrict__ scratch,
                                 int N) {
    __shared__ unsigned int buf[K4CAP];
    __shared__ int cnt[BINW], pref[BINW], tmp[BINW];
    int b = blockIdx.x;
    int t = threadIdx.x;
    int p0 = binBaseC[b], p1 = binBaseC[b + 1];
    int sz = p1 - p0;
    const unsigned int* src;
    if (sz <= K4CAP) {
        for (int i = t; i < sz; i += THREADS) buf[i] = A[p0 + i];
        src = buf;
    } else {
        unsigned int* sc = scratch + (size_t)(b & 63) * SLOTU;
        for (int i = t; i < sz && i < SLOTU; i += THREADS) sc[i] = A[p0 + i];
        src = sc;
    }
    if (t < BINW) cnt[t] = 0;
    __syncthreads();
    for (int i = t; i < sz; i += THREADS)
        atomicAdd(&cnt[(src[i] >> 18) & (BINW - 1)], 1);
    __syncthreads();
    int v = (t < BINW) ? cnt[t] : 0;
    if (t < BINW) tmp[t] = v;
    __syncthreads();
    for (int d = 1; d < BINW; d <<= 1) {
        int u = (t >= d && t < BINW) ? tmp[t - d] : 0;
        __syncthreads();
        if (t < BINW) tmp[t] += u;
        __syncthreads();
    }
    if (t < BINW) pref[t] = tmp[t] - v;
    int node = (b << SH) + t;
    if (t < BINW && node < N) off[node] = p0 + pref[t];
    __syncthreads();
    for (int i = t; i < sz; i += THREADS) {
        unsigned int a = src[i];
        int cl = (a >> 18) & (BINW - 1);
        int p = atomicAdd(&pref[cl], 1);
        A[(size_t)p0 + p] = a & 0x3FFFFu;
    }
}

// ======================= 4-lane cooperative fused gather + dense =======================

// quad per dest node; each lane strides the adjacency list by 4 and gathers full rows
__global__ void gather_dense1_w4(const int* __restrict__ off, const int* __restrict__ csr_src,
                                 const float* __restrict__ dis, const float* __restrict__ x,
                                 const float* __restrict__ W0, const float* __restrict__ W1,
                                 const float* __restrict__ b, float* __restrict__ h1,
                                 int N, int E) {
    __shared__ float sW0[128], sW1[128], sb[16];
    for (int i = threadIdx.x; i < 128; i += blockDim.x) { sW0[i] = W0[i]; sW1[i] = W1[i]; }
    if (threadIdx.x < 16) sb[threadIdx.x] = b[threadIdx.x];
    __syncthreads();
    int t = blockIdx.x * blockDim.x + threadIdx.x;
    int g = t >> 2, sub = t & 3;
    if (g >= N) return;
    int p0 = __builtin_nontemporal_load(&off[g]);
    int p1 = (g == N - 1) ? E : __builtin_nontemporal_load(&off[g + 1]);
    float tx[8] = {0, 0, 0, 0, 0, 0, 0, 0};
    for (int p = p0 + sub; p < p1; p += 4) {
        int src = __builtin_nontemporal_load(&csr_src[p]);
        float wv = dis[src];
        const float4* fr = reinterpret_cast<const float4*>(x + (size_t)src * 8);
        float4 a = fr[0], bb = fr[1];
        tx[0] += wv * a.x;  tx[1] += wv * a.y;  tx[2] += wv * a.z;  tx[3] += wv * a.w;
        tx[4] += wv * bb.x; tx[5] += wv * bb.y; tx[6] += wv * bb.z; tx[7] += wv * bb.w;
    }
#pragma unroll
    for (int i = 0; i < 8; ++i) {
        tx[i] += __shfl_xor(tx[i], 1);
        tx[i] += __shfl_xor(tx[i], 2);
    }
    float xa[8];
    const float4* xr = reinterpret_cast<const float4*>(x + (size_t)g * 8);
    float4 a = xr[0], bb = xr[1];
    xa[0] = a.x; xa[1] = a.y; xa[2] = a.z; xa[3] = a.w;
    xa[4] = bb.x; xa[5] = bb.y; xa[6] = bb.z; xa[7] = bb.w;
    float sc = -dis[g];
    int ob = sub * 4;
    float acc[4];
#pragma unroll
    for (int j = 0; j < 4; ++j) acc[j] = sb[ob + j];
#pragma unroll
    for (int f = 0; f < 8; ++f) {
        float xv = xa[f], tv = sc * tx[f];
#pragma unroll
        for (int j = 0; j < 4; ++j) acc[j] += xv * sW0[f * 16 + ob + j] + tv * sW1[f * 16 + ob + j];
    }
    float4 q;
    q.x = fmaxf(acc[0], 0.f); q.y = fmaxf(acc[1], 0.f);
    q.z = fmaxf(acc[2], 0.f); q.w = fmaxf(acc[3], 0.f);
    reinterpret_cast<float4*>(h1 + (size_t)g * 16)[sub] = q;
}

__global__ void gather_dense2_w4(const int* __restrict__ off, const int* __restrict__ csr_src,
                                 const float* __restrict__ dis, const float* __restrict__ h1,
                                 const float* __restrict__ W0, const float* __restrict__ W1,
                                 const float* __restrict__ b, const float* __restrict__ Wr,
                                 const float* __restrict__ br, float* __restrict__ s,
                                 int N, int E) {
    __shared__ float sW0[256], sW1[256], sb[16], sWr[16], sbr;
    for (int i = threadIdx.x; i < 256; i += blockDim.x) { sW0[i] = W0[i]; sW1[i] = W1[i]; }
    if (threadIdx.x < 16) { sb[threadIdx.x] = b[threadIdx.x]; sWr[threadIdx.x] = Wr[threadIdx.x]; }
    if (threadIdx.x == 0) sbr = br[0];
    __syncthreads();
    int t = blockIdx.x * blockDim.x + threadIdx.x;
    int g = t >> 2, sub = t & 3;
    if (g >= N) return;
    int p0 = __builtin_nontemporal_load(&off[g]);
    int p1 = (g == N - 1) ? E : __builtin_nontemporal_load(&off[g + 1]);
    float tx[16];
#pragma unroll
    for (int o = 0; o < 16; ++o) tx[o] = 0.f;
    for (int p = p0 + sub; p < p1; p += 4) {
        int src = __builtin_nontemporal_load(&csr_src[p]);
        float wv = dis[src];
        const float4* fr = reinterpret_cast<const float4*>(h1 + (size_t)src * 16);
#pragma unroll
        for (int v = 0; v < 4; ++v) {
            float4 q = fr[v];
            tx[v * 4 + 0] += wv * q.x;
            tx[v * 4 + 1] += wv * q.y;
            tx[v * 4 + 2] += wv * q.z;
            tx[v * 4 + 3] += wv * q.w;
        }
    }
#pragma unroll
    for (int i = 0; i < 16; ++i) {
        tx[i] += __shfl_xor(tx[i], 1);
        tx[i] += __shfl_xor(tx[i], 2);
    }
    float ha[16];
    const float4* hr = reinterpret_cast<const float4*>(h1 + (size_t)g * 16);
#pragma unroll
    for (int v = 0; v < 4; ++v) {
        float4 q = hr[v];
        ha[v * 4 + 0] = q.x; ha[v * 4 + 1] = q.y; ha[v * 4 + 2] = q.z; ha[v * 4 + 3] = q.w;
    }
    float sc = -dis[g];
    int ob = sub * 4;
    float acc[4];
#pragma unroll
    for (int j = 0; j < 4; ++j) acc[j] = sb[ob + j];
#pragma unroll
    for (int f = 0; f < 16; ++f) {
        float hv = ha[f], tv = sc * tx[f];
#pragma unroll
        for (int j = 0; j < 4; ++j) acc[j] += hv * sW0[f * 16 + ob + j] + tv * sW1[f * 16 + ob + j];
    }
    float sv = 0.f;
#pragma unroll
    for (int j = 0; j < 4; ++j) sv += fmaxf(acc[j], 0.f) * sWr[ob + j];
    sv += __shfl_xor(sv, 1);
    sv += __shfl_xor(sv, 2);
    if (sub == 0) s[g] = sv + sbr;
}

__global__ void softmax_kernel(const float* __restrict__ s, const int* __restrict__ batch,
                               float* __restrict__ out, int N) {
    int g = blockIdx.x;
    __shared__ float red[THREADS];
    int lo, hi;
    { int a = 0, b = N; while (a < b) { int mid = (a + b) >> 1; if (batch[mid] < g) a = mid + 1; else b = mid; } lo = a; }
    { int a = lo, b = N; while (a < b) { int mid = (a + b) >> 1; if (batch[mid] < g + 1) a = mid + 1; else b = mid; } hi = a; }
    float mx = -INFINITY;
    for (int i = lo + threadIdx.x; i < hi; i += THREADS) mx = fmaxf(mx, s[i]);
    red[threadIdx.x] = mx;
    __syncthreads();
    for (int d = THREADS / 2; d > 0; d >>= 1) {
        if (threadIdx.x < d) red[threadIdx.x] = fmaxf(red[threadIdx.x], red[threadIdx.x + d]);
        __syncthreads();
    }
    mx = red[0];
    __syncthreads();
    float sum = 0.f;
    for (int i = lo + threadIdx.x; i < hi; i += THREADS) sum += expf(s[i] - mx);
    red[threadIdx.x] = sum;
    __syncthreads();
    for (int d = THREADS / 2; d > 0; d >>= 1) {
        if (threadIdx.x < d) red[threadIdx.x] += red[threadIdx.x + d];
        __syncthreads();
    }
    float inv = 1.f / red[0];
    for (int i = lo + threadIdx.x; i < hi; i += THREADS) out[i] = expf(s[i] - mx) * inv;
}

// ======================= fallback: round-2 atomic CSR build + fused gathers =======================

__global__ void deg_cnt_kernel(const int* __restrict__ row, const int* __restrict__ col,
                               int* __restrict__ deg_i, int* __restrict__ cnt, int E) {
    int e = blockIdx.x * blockDim.x + threadIdx.x;
    if (e >= E) return;
    atomicAdd(&deg_i[row[e]], 1);
    atomicAdd(&cnt[col[e]], 1);
}

__global__ void dis_kernel_i(const int* __restrict__ deg_i, float* __restrict__ dis, int N) {
    int i = blockIdx.x * blockDim.x + threadIdx.x;
    if (i < N) {
        int d = deg_i[i];
        dis[i] = d > 0 ? rsqrtf((float)d) : 0.f;
    }
}

__global__ void scan1_kernel(const int* __restrict__ cnt, int* __restrict__ off,
                             int* __restrict__ bsum, int n) {
    __shared__ int tmp[THREADS];
    int i = blockIdx.x * THREADS + threadIdx.x;
    int v = (i < n) ? cnt[i] : 0;
    tmp[threadIdx.x] = v;
    __syncthreads();
    for (int d = 1; d < THREADS; d <<= 1) {
        int t = (threadIdx.x >= d) ? tmp[threadIdx.x - d] : 0;
        __syncthreads();
        tmp[threadIdx.x] += t;
        __syncthreads();
    }
    if (i < n) off[i] = tmp[threadIdx.x] - v;
    if (threadIdx.x == THREADS - 1) bsum[blockIdx.x] = tmp[threadIdx.x];
}

__global__ void scan2_kernel(int* __restrict__ bsum, int nb) {
    __shared__ int tmp[1024];
    int carry = 0;
    for (int base = 0; base < nb; base += 1024) {
        int i = base + threadIdx.x;
        int v = (i < nb) ? bsum[i] : 0;
        tmp[threadIdx.x] = v;
        __syncthreads();
        for (int d = 1; d < 1024; d <<= 1) {
            int t = (threadIdx.x >= d) ? tmp[threadIdx.x - d] : 0;
            __syncthreads();
            tmp[threadIdx.x] += t;
            __syncthreads();
        }
        if (i < nb) bsum[i] = carry + tmp[threadIdx.x] - v;
        carry += tmp[1023];
        __syncthreads();
    }
}

__global__ void scan3_kernel(int* __restrict__ off, const int* __restrict__ bsum, int n) {
    int i = blockIdx.x * THREADS + threadIdx.x;
    if (i < n) off[i] += bsum[blockIdx.x];
}

__global__ void fill_csr_kernel(const int* __restrict__ row, const int* __restrict__ col,
                                const int* __restrict__ off, int* __restrict__ fill,
                                int* __restrict__ csr_src, int E) {
    int e = blockIdx.x * blockDim.x + threadIdx.x;
    if (e >= E) return;
    int c = col[e];
    int p = off[c] + atomicAdd(&fill[c], 1);
    csr_src[p] = row[e];
}

// ======================= launch =======================

extern "C" void kernel_launch(void* const* d_in, const int* in_sizes, int n_in,
                              void* d_out, int out_size, void* d_ws, size_t ws_size,
                              hipStream_t stream) {
    const float* x     = (const float*)d_in[0];
    const int*   ei    = (const int*)d_in[1];
    const int*   batch = (const int*)d_in[2];
    const float* W1_0  = (const float*)d_in[3];
    const float* W1_1  = (const float*)d_in[4];
    const float* b1    = (const float*)d_in[5];
    const float* W2_0  = (const float*)d_in[6];
    const float* W2_1  = (const float*)d_in[7];
    const float* b2    = (const float*)d_in[8];
    const float* Wr    = (const float*)d_in[9];
    const float* br    = (const float*)d_in[10];
    float* out = (float*)d_out;

    const int N = in_sizes[2];
    const int E = in_sizes[1] / 2;
    const int G = 256;
    const int* row = ei;
    const int* col = ei + E;

    const int gN = (N + THREADS - 1) / THREADS;
    const int gE = (E + THREADS - 1) / THREADS;
    const int gW = ((size_t)N * 4 + THREADS - 1) / THREADS;   // quad-per-node grids
    const int NBIN = (N + BINW - 1) >> SH;
    const int NBLK = (E + CHUNK - 1) / CHUNK;

    // fast-path layout (round-4 proven)
    size_t offB = 0;
    auto alloc = [&](size_t bytes) { size_t p = offB; offB += (bytes + 255) & ~(size_t)255; return p; };
    size_t pA    = alloc((size_t)E * 4);            // packed pairs -> csr (aliased)
    size_t pCu8  = alloc((size_t)E);                // row-binned low bytes
    size_t pOff  = alloc((size_t)N * 4);
    size_t pDis  = alloc((size_t)N * 4);
    size_t pS    = alloc((size_t)N * 4);
    size_t pTotC = alloc((size_t)NBIN * 4);
    size_t pBasC = alloc((size_t)(NBIN + 1) * 4);
    size_t pTotR = alloc((size_t)NBIN * 4);
    size_t pBasR = alloc((size_t)(NBIN + 1) * 4);
    size_t uni   = (size_t)2 * NBLK * NBIN * 4;     // Dcol+Drow
    size_t uh1   = (size_t)16 * N * 4;              // h1
    size_t usc   = (size_t)64 * SLOTU * 4;          // scratch slots
    size_t uMax  = uni > uh1 ? uni : uh1; if (usc > uMax) uMax = usc;
    size_t pUni  = alloc(uMax);
    size_t need_fast = offB;

    if (N <= (1 << 18) && NBIN <= MAXBIN && ws_size >= need_fast) {
        char* base = (char*)d_ws;
        unsigned int* A    = (unsigned int*)(base + pA);
        unsigned char* Cu8 = (unsigned char*)(base + pCu8);
        int* off   = (int*)(base + pOff);
        float* dis = (float*)(base + pDis);
        float* s   = (float*)(base + pS);
        int* totC  = (int*)(base + pTotC);
        int* basC  = (int*)(base + pBasC);
        int* totR  = (int*)(base + pTotR);
        int* basR  = (int*)(base + pBasR);
        int* Dcol  = (int*)(base + pUni);
        int* Drow  = Dcol + (size_t)NBLK * NBIN;
        float* h1  = (float*)(base + pUni);
        unsigned int* scratch = (unsigned int*)(base + pUni);

        int gAB = (int)(((size_t)NBLK * NBIN + THREADS - 1) / THREADS);

        hist_kernel<<<NBLK, THREADS, 0, stream>>>(row, col, Dcol, Drow, E, NBIN);
        scan_col_kernel<<<NBIN, THREADS, 0, stream>>>(Dcol, totC, NBLK, NBIN);
        scan_col_kernel<<<NBIN, THREADS, 0, stream>>>(Drow, totR, NBLK, NBIN);
        scan_bins_kernel<<<1, 1024, 0, stream>>>(totC, basC, NBIN);
        scan_bins_kernel<<<1, 1024, 0, stream>>>(totR, basR, NBIN);
        add_base_kernel<<<gAB, THREADS, 0, stream>>>(Dcol, basC, NBLK, NBIN);
        add_base_kernel<<<gAB, THREADS, 0, stream>>>(Drow, basR, NBLK, NBIN);
        scatter_kernel<<<NBLK, THREADS, 0, stream>>>(row, col, Dcol, Drow, A, Cu8, E, NBIN);
        deg_bins_kernel<<<NBIN, THREADS, 0, stream>>>(Cu8, basR, dis, N);
        csr_place_kernel<<<NBIN, THREADS, 0, stream>>>(A, basC, off, scratch, N);
        gather_dense1_w4<<<gW, THREADS, 0, stream>>>(off, (const int*)A, dis, x, W1_0, W1_1, b1, h1, N, E);
        gather_dense2_w4<<<gW, THREADS, 0, stream>>>(off, (const int*)A, dis, h1, W2_0, W2_1, b2, Wr, br, s, N, E);
        softmax_kernel<<<G, THREADS, 0, stream>>>(s, batch, out, N);
    } else {
        // fallback: round-2 atomic CSR path
        int* deg_i = (int*)d_ws;
        int* cnt   = deg_i + N;
        int* fill  = cnt + N;
        int* off   = fill + N;
        int* bsum  = off + N;
        float* dis = (float*)(bsum + 1024);
        float* h1  = dis + N;
        float* s   = h1 + (size_t)16 * N;
        int* csr   = (int*)(s + N);

        hipMemsetAsync(deg_i, 0, sizeof(int) * (size_t)3 * N, stream);

        deg_cnt_kernel<<<gE, THREADS, 0, stream>>>(row, col, deg_i, cnt, E);
        dis_kernel_i<<<gN, THREADS, 0, stream>>>(deg_i, dis, N);
        scan1_kernel<<<gN, THREADS, 0, stream>>>(cnt, off, bsum, N);
        scan2_kernel<<<1, 1024, 0, stream>>>(bsum, gN);
        scan3_kernel<<<gN, THREADS, 0, stream>>>(off, bsum, N);
        fill_csr_kernel<<<gE, THREADS, 0, stream>>>(row, col, off, fill, csr, E);
        gather_dense1_w4<<<gW, THREADS, 0, stream>>>(off, csr, dis, x, W1_0, W1_1, b1, h1, N, E);
        gather_dense2_w4<<<gW, THREADS, 0, stream>>>(off, csr, dis, h1, W2_0, W2_1, b2, Wr, br, s, N, E);
        softmax_kernel<<<G, THREADS, 0, stream>>>(s, batch, out, N);
    }
}